// Round 1
// baseline (622.629 us; speedup 1.0000x reference)
//
#include <hip/hip_runtime.h>

// out = ((1 + cos)/2 + 1e-8)/0.05 = 10*cos + 10 + 2e-7
// cos = normalize(emb) @ normalize(weight)^T
// emb: 65536x768 f32, weight: 1024x768 f32, out: 65536x1024 f32

#define N_EMB 65536
#define N_W   1024
#define DIM   768

typedef __attribute__((ext_vector_type(4))) float f32x4;
typedef __attribute__((ext_vector_type(8))) __bf16 bf16x8;

__device__ __forceinline__ unsigned short f2bf(float x) {
    unsigned int u = __float_as_uint(x);
    u += 0x7FFF + ((u >> 16) & 1);      // round-to-nearest-even
    return (unsigned short)(u >> 16);
}

// One wave per row: L2-normalize + cast to bf16.
// Rows [0,65536) -> emb->A ; rows [65536, 66560) -> weight->B
__global__ __launch_bounds__(256) void norm_cast_kernel(
    const float* __restrict__ emb, const float* __restrict__ weight,
    unsigned short* __restrict__ A, unsigned short* __restrict__ B)
{
    const int wave = threadIdx.x >> 6;
    const int lane = threadIdx.x & 63;
    int row = blockIdx.x * 4 + wave;
    const float* src;
    unsigned short* dst;
    if (row < N_EMB) {
        src = emb + (size_t)row * DIM;
        dst = A + (size_t)row * DIM;
    } else {
        int r = row - N_EMB;
        src = weight + (size_t)r * DIM;
        dst = B + (size_t)r * DIM;
    }
    const float4* s4 = (const float4*)src;
    float4 v[3];
    float ss = 0.f;
#pragma unroll
    for (int i = 0; i < 3; i++) {
        v[i] = s4[lane + 64 * i];
        ss += v[i].x * v[i].x + v[i].y * v[i].y + v[i].z * v[i].z + v[i].w * v[i].w;
    }
#pragma unroll
    for (int off = 32; off > 0; off >>= 1) ss += __shfl_xor(ss, off);
    float scale = 1.0f / fmaxf(sqrtf(ss), 1e-8f);
    ushort4* d4 = (ushort4*)dst;
#pragma unroll
    for (int i = 0; i < 3; i++) {
        ushort4 o;
        o.x = f2bf(v[i].x * scale);
        o.y = f2bf(v[i].y * scale);
        o.z = f2bf(v[i].z * scale);
        o.w = f2bf(v[i].w * scale);
        d4[lane + 64 * i] = o;
    }
}

__device__ __forceinline__ void async16(const void* g, void* l) {
    __builtin_amdgcn_global_load_lds(
        (const __attribute__((address_space(1))) void*)g,
        (__attribute__((address_space(3))) void*)l, 16, 0, 0);
}

// C[M=65536, N=1024] = A[M,768] @ B[N,768]^T, both bf16 row-major (K contiguous).
// 128x128 block tile, BK=32, 256 threads = 4 waves in 2x2, each wave 64x64 via
// 4x4 grid of 16x16x32 MFMAs. LDS layout [ko=4][m=128][8bf16] -> conflict-free
// ds_read_b128 and sequential global_load_lds destinations.
__global__ __launch_bounds__(256) void cos_gemm_kernel(
    const unsigned short* __restrict__ A, const unsigned short* __restrict__ B,
    float* __restrict__ out)
{
    __shared__ bf16x8 As[512];   // [ko][m] 8KB
    __shared__ bf16x8 Bs[512];   // [ko][n] 8KB
    const int t = threadIdx.x;
    const int lane = t & 63, wave = t >> 6;
    const int wm = wave & 1, wn = wave >> 1;
    const int row0 = blockIdx.y * 128, col0 = blockIdx.x * 128;
    const int quad = lane >> 4, l16 = lane & 15;

    // staging: slot s (0..511): ko = s>>7, m = s&127. Thread t covers s=t and s=t+256
    // (same m, ko+2 => global k offset +16 elements).
    const unsigned short* Ag = A + (size_t)(row0 + (t & 127)) * DIM + ((t >> 7) * 8);
    const unsigned short* Bg = B + (size_t)(col0 + (t & 127)) * DIM + ((t >> 7) * 8);

    f32x4 acc[4][4] = {};

    for (int k0 = 0; k0 < DIM; k0 += 32) {
        async16(Ag + k0,      &As[t]);
        async16(Ag + k0 + 16, &As[t + 256]);
        async16(Bg + k0,      &Bs[t]);
        async16(Bg + k0 + 16, &Bs[t + 256]);
        __syncthreads();   // drains vmcnt then barrier

        bf16x8 af[4], bfr[4];
#pragma unroll
        for (int i = 0; i < 4; i++) af[i]  = As[quad * 128 + wm * 64 + i * 16 + l16];
#pragma unroll
        for (int j = 0; j < 4; j++) bfr[j] = Bs[quad * 128 + wn * 64 + j * 16 + l16];
#pragma unroll
        for (int i = 0; i < 4; i++)
#pragma unroll
            for (int j = 0; j < 4; j++)
                acc[i][j] = __builtin_amdgcn_mfma_f32_16x16x32_bf16(af[i], bfr[j], acc[i][j], 0, 0, 0);
        __syncthreads();   // LDS reads done before next iter overwrites
    }

    // C/D layout: col = lane&15, row = (lane>>4)*4 + reg
#pragma unroll
    for (int i = 0; i < 4; i++) {
#pragma unroll
        for (int r = 0; r < 4; r++) {
            int row = row0 + wm * 64 + i * 16 + quad * 4 + r;
            float* orow = out + (size_t)row * N_W + col0 + wn * 64 + l16;
#pragma unroll
            for (int j = 0; j < 4; j++)
                orow[j * 16] = fmaf(acc[i][j][r], 10.0f, 10.0f);
        }
    }
}

extern "C" void kernel_launch(void* const* d_in, const int* in_sizes, int n_in,
                              void* d_out, int out_size, void* d_ws, size_t ws_size,
                              hipStream_t stream) {
    const float* emb    = (const float*)d_in[0];
    const float* weight = (const float*)d_in[1];
    unsigned short* A = (unsigned short*)d_ws;                       // 65536*768 bf16
    unsigned short* B = A + (size_t)N_EMB * DIM;                     // 1024*768 bf16
    float* out = (float*)d_out;

    norm_cast_kernel<<<(N_EMB + N_W) / 4, 256, 0, stream>>>(emb, weight, A, B);
    cos_gemm_kernel<<<dim3(N_W / 128, N_EMB / 128), 256, 0, stream>>>(A, B, out);
}

// Round 2
// 605.670 us; speedup vs baseline: 1.0280x; 1.0280x over previous
//
#include <hip/hip_runtime.h>

// out = ((1 + cos)/2 + 1e-8)/0.05 = 10*cos + 10 + 2e-7
// cos = normalize(emb) @ normalize(weight)^T
// emb: 65536x768 f32, weight: 1024x768 f32, out: 65536x1024 f32

#define N_EMB 65536
#define N_W   1024
#define DIM   768

typedef __attribute__((ext_vector_type(4))) float f32x4;
typedef __attribute__((ext_vector_type(8))) __bf16 bf16x8;

__device__ __forceinline__ unsigned short f2bf(float x) {
    unsigned int u = __float_as_uint(x);
    u += 0x7FFF + ((u >> 16) & 1);      // round-to-nearest-even
    return (unsigned short)(u >> 16);
}

// One wave per row: L2-normalize + cast to bf16.
// Rows [0,65536) -> emb->A ; rows [65536, 66560) -> weight->B
__global__ __launch_bounds__(256) void norm_cast_kernel(
    const float* __restrict__ emb, const float* __restrict__ weight,
    unsigned short* __restrict__ A, unsigned short* __restrict__ B)
{
    const int wave = threadIdx.x >> 6;
    const int lane = threadIdx.x & 63;
    int row = blockIdx.x * 4 + wave;
    const float* src;
    unsigned short* dst;
    if (row < N_EMB) {
        src = emb + (size_t)row * DIM;
        dst = A + (size_t)row * DIM;
    } else {
        int r = row - N_EMB;
        src = weight + (size_t)r * DIM;
        dst = B + (size_t)r * DIM;
    }
    const float4* s4 = (const float4*)src;
    float4 v[3];
    float ss = 0.f;
#pragma unroll
    for (int i = 0; i < 3; i++) {
        v[i] = s4[lane + 64 * i];
        ss += v[i].x * v[i].x + v[i].y * v[i].y + v[i].z * v[i].z + v[i].w * v[i].w;
    }
#pragma unroll
    for (int off = 32; off > 0; off >>= 1) ss += __shfl_xor(ss, off);
    float scale = 1.0f / fmaxf(sqrtf(ss), 1e-8f);
    ushort4* d4 = (ushort4*)dst;
#pragma unroll
    for (int i = 0; i < 3; i++) {
        ushort4 o;
        o.x = f2bf(v[i].x * scale);
        o.y = f2bf(v[i].y * scale);
        o.z = f2bf(v[i].z * scale);
        o.w = f2bf(v[i].w * scale);
        d4[lane + 64 * i] = o;
    }
}

__device__ __forceinline__ void async16(const void* g, void* l) {
    __builtin_amdgcn_global_load_lds(
        (const __attribute__((address_space(1))) void*)g,
        (__attribute__((address_space(3))) void*)l, 16, 0, 0);
}

// C[M=65536, N=1024] = A[M,768] @ B[N,768]^T, both bf16 row-major (K contiguous).
// 128x128 block tile, BK=32, 256 threads = 4 waves in 2x2, each wave 64x64 via
// 4x4 grid of 16x16x32 MFMAs. LDS layout [ko=4][m=128][8bf16] -> conflict-free
// ds_read_b128 and sequential global_load_lds destinations.
//
// XCD-aware swizzle: dispatch round-robins blocks across the 8 XCDs by linear
// id. Map b -> xcd=b&7, s=b>>3, row_tile = xcd*64 + s/8, col_tile = s%8, so
// each XCD processes the 8 column tiles of one row-tile back to back: the A
// row-tile (196 KB) and the whole B (1.5 MB) stay resident in its 4 MB L2.
// A is then fetched once (100 MB) instead of ~4x.
__global__ __launch_bounds__(256) void cos_gemm_kernel(
    const unsigned short* __restrict__ A, const unsigned short* __restrict__ B,
    float* __restrict__ out)
{
    __shared__ bf16x8 As[512];   // [ko][m] 8KB
    __shared__ bf16x8 Bs[512];   // [ko][n] 8KB
    const int t = threadIdx.x;
    const int lane = t & 63, wave = t >> 6;
    const int wm = wave & 1, wn = wave >> 1;

    const int b = blockIdx.x;
    const int xcd = b & 7;
    const int s = b >> 3;
    const int row0 = (xcd * 64 + (s >> 3)) * 128;
    const int col0 = (s & 7) * 128;

    const int quad = lane >> 4, l16 = lane & 15;

    // staging: slot s (0..511): ko = s>>7, m = s&127. Thread t covers s=t and s=t+256
    // (same m, ko+2 => global k offset +16 elements).
    const unsigned short* Ag = A + (size_t)(row0 + (t & 127)) * DIM + ((t >> 7) * 8);
    const unsigned short* Bg = B + (size_t)(col0 + (t & 127)) * DIM + ((t >> 7) * 8);

    f32x4 acc[4][4] = {};

    for (int k0 = 0; k0 < DIM; k0 += 32) {
        async16(Ag + k0,      &As[t]);
        async16(Ag + k0 + 16, &As[t + 256]);
        async16(Bg + k0,      &Bs[t]);
        async16(Bg + k0 + 16, &Bs[t + 256]);
        __syncthreads();   // drains vmcnt then barrier

        bf16x8 af[4], bfr[4];
#pragma unroll
        for (int i = 0; i < 4; i++) af[i]  = As[quad * 128 + wm * 64 + i * 16 + l16];
#pragma unroll
        for (int j = 0; j < 4; j++) bfr[j] = Bs[quad * 128 + wn * 64 + j * 16 + l16];
#pragma unroll
        for (int i = 0; i < 4; i++)
#pragma unroll
            for (int j = 0; j < 4; j++)
                acc[i][j] = __builtin_amdgcn_mfma_f32_16x16x32_bf16(af[i], bfr[j], acc[i][j], 0, 0, 0);
        __syncthreads();   // LDS reads done before next iter overwrites
    }

    // C/D layout: col = lane&15, row = (lane>>4)*4 + reg
    // Non-temporal: C is write-once, keep it out of L2 so A/B stay resident.
#pragma unroll
    for (int i = 0; i < 4; i++) {
#pragma unroll
        for (int r = 0; r < 4; r++) {
            int row = row0 + wm * 64 + i * 16 + quad * 4 + r;
            float* orow = out + (size_t)row * N_W + col0 + wn * 64 + l16;
#pragma unroll
            for (int j = 0; j < 4; j++)
                __builtin_nontemporal_store(fmaf(acc[i][j][r], 10.0f, 10.0f), orow + j * 16);
        }
    }
}

extern "C" void kernel_launch(void* const* d_in, const int* in_sizes, int n_in,
                              void* d_out, int out_size, void* d_ws, size_t ws_size,
                              hipStream_t stream) {
    const float* emb    = (const float*)d_in[0];
    const float* weight = (const float*)d_in[1];
    unsigned short* A = (unsigned short*)d_ws;                       // 65536*768 bf16
    unsigned short* B = A + (size_t)N_EMB * DIM;                     // 1024*768 bf16
    float* out = (float*)d_out;

    norm_cast_kernel<<<(N_EMB + N_W) / 4, 256, 0, stream>>>(emb, weight, A, B);
    cos_gemm_kernel<<<4096, 256, 0, stream>>>(A, B, out);
}